// Round 3
// baseline (239.132 us; speedup 1.0000x reference)
//
#include <hip/hip_runtime.h>
#include <math.h>

// ---------------------------------------------------------------------------
// QFCModel fused: avgpool(6) -> linear(16->4) -> 4-qubit circuit -> linear -> BN
//
// Circuit collapse: state = U_var @ (RX(z0)⊗..⊗RX(z3))|0>
//   amp_k = (-i)^popcount(k) * r_k, r real product of cos/sin(z/2)
//   V = U_var * diag((-i)^popc)  -> probs_i = (Vr r)_i^2 + (Vi r)_i^2
//   out_j = cls_b[j] + sum_i W2[j,i] probs_i, W2[j,i] = sum_w cls_w[j,w]*sign_w(i)
//
// R3 layout: block=256 threads owns 16 samples. STAGE rows 0..23 of each
// sample (one contiguous 2688B run) into LDS with consecutive-lane-consecutive-
// address float4 loads (fixes R2's 64-lines-per-instruction scatter that
// pinned the kernel at 1.1 TB/s). Then thread (s,cell) pools its 6x6 window
// from LDS, shfl_xor-reduces the encode, computes matvec row i=cell against
// LDS V (stride 17 -> conflict-free), shfl_xor-reduces the output.
// ---------------------------------------------------------------------------

#define BTOT 32768
#define SPB  16           // samples per block
#define SSTR 676          // LDS floats per sample (672 used, pad to keep
                          // 16B alignment and 4-bank sample skew: 676%32=4)

__global__ __launch_bounds__(256) void fused_kernel(
    const float* __restrict__ x,
    const float* __restrict__ enc_w, const float* __restrict__ enc_b,
    const float* __restrict__ qparams,
    const float* __restrict__ cls_w, const float* __restrict__ cls_b,
    float* __restrict__ preBN, float* __restrict__ sums)
{
    __shared__ float sx[SPB * SSTR];     // 43264 B staged image rows 0..23
    __shared__ float sVr[16 * 17];       // V real, stride 17 (17i mod 32 injective)
    __shared__ float sVi[16 * 17];
    __shared__ float sW2[4 * 17];
    __shared__ float red[4][8];

    const int tid = threadIdx.x;

    // ---- prep: lanes of wave 0 build W2 and V into LDS -------------------
    if (tid < 64) {
        int j = tid >> 4, i = tid & 15;
        float acc = 0.f;
        #pragma unroll
        for (int w = 0; w < 4; ++w)
            acc += cls_w[j * 4 + w] * ((i & (8 >> w)) ? -1.f : 1.f);
        sW2[j * 17 + i] = acc;
    }
    if (tid < 16) {
        // simulate variational layers on basis state e_tid -> column tid of U
        float pr[16], pi[16];
        #pragma unroll
        for (int i = 0; i < 16; ++i) { pr[i] = (i == tid) ? 1.f : 0.f; pi[i] = 0.f; }
        for (int layer = 0; layer < 3; ++layer) {
            for (int w = 0; w < 4; ++w) {
                const float* qp = qparams + (layer * 4 + w) * 3;
                float phi = qp[0], th = qp[1], om = qp[2];
                float c, s, ca, sa, cd, sd;
                sincosf(0.5f * th, &s, &c);
                sincosf(0.5f * (phi + om), &sa, &ca);
                sincosf(0.5f * (phi - om), &sd, &cd);
                float u00r =  c * ca, u00i = -c * sa;
                float u01r = -s * cd, u01i = -s * sd;
                float u10r =  s * cd, u10i = -s * sd;
                float u11r =  c * ca, u11i =  c * sa;
                int m = 8 >> w;   // wire 0 = MSB
                for (int idx = 0; idx < 16; ++idx) {
                    if (idx & m) continue;
                    int i1 = idx | m;
                    float ar = pr[idx], ai = pi[idx], br = pr[i1], bi = pi[i1];
                    pr[idx] = u00r*ar - u00i*ai + u01r*br - u01i*bi;
                    pi[idx] = u00r*ai + u00i*ar + u01r*bi + u01i*br;
                    pr[i1]  = u10r*ar - u10i*ai + u11r*br - u11i*bi;
                    pi[i1]  = u10r*ai + u10i*ar + u11r*bi + u11i*br;
                }
            }
            for (int w = 0; w < 3; ++w) {  // CNOT ladder
                int mc = 8 >> w, mt = 8 >> (w + 1);
                for (int idx = 0; idx < 16; ++idx) {
                    if ((idx & mc) && !(idx & mt)) {
                        int i1 = idx | mt;
                        float tr = pr[idx], ti = pi[idx];
                        pr[idx] = pr[i1]; pi[idx] = pi[i1];
                        pr[i1] = tr;      pi[i1] = ti;
                    }
                }
            }
        }
        // fold (-i)^popcount(column tid); store V[i][tid]
        int p = __popc(tid) & 3;
        #pragma unroll
        for (int i = 0; i < 16; ++i) {
            float re = pr[i], im = pi[i], vr, vi;
            if (p == 0)      { vr = re;  vi = im;  }
            else if (p == 1) { vr = im;  vi = -re; }
            else if (p == 2) { vr = -re; vi = -im; }
            else             { vr = -im; vi = re;  }
            sVr[i * 17 + tid] = vr;
            sVi[i * 17 + tid] = vi;
        }
    }

    // ---- stage: rows 0..23 of 16 samples, fully coalesced float4 ---------
    // per sample: 168 float4 (one contiguous 2688B run); block total 2688 f4
    const int s0 = blockIdx.x * SPB;
    const float4* xb = (const float4*)x;
    #pragma unroll
    for (int it = 0; it < 11; ++it) {
        int gid = it * 256 + tid;
        if (gid < SPB * 168) {
            int c = gid / 168;          // sample within block
            int o = gid - c * 168;      // float4 offset within rows 0..23
            float4 v = xb[(size_t)(s0 + c) * 196 + o];
            *(float4*)&sx[c * SSTR + o * 4] = v;
        }
    }
    __syncthreads();

    // ---- pool: thread (s, cell) sums its 6x6 window from LDS -------------
    const int s = tid >> 4, cell = tid & 15;
    const int cr = cell >> 2, cc = cell & 3;
    const float* sb = &sx[s * SSTR + cr * 6 * 28 + cc * 6];
    float sum = 0.f;
    #pragma unroll
    for (int r = 0; r < 6; ++r) {
        const float* rp = sb + r * 28;
        sum += (rp[0] + rp[1]) + (rp[2] + rp[3]) + (rp[4] + rp[5]);
    }
    const float pv = sum * (1.f / 36.f);

    // ---- encode: z_j = sum_cells enc_w[j][cell] * pv, xor-reduce 16 lanes -
    float z[4];
    #pragma unroll
    for (int j = 0; j < 4; ++j) z[j] = enc_w[j * 16 + cell] * pv;
    #pragma unroll
    for (int m = 1; m <= 8; m <<= 1) {
        #pragma unroll
        for (int j = 0; j < 4; ++j) z[j] += __shfl_xor(z[j], m, 64);
    }
    #pragma unroll
    for (int j = 0; j < 4; ++j) z[j] += enc_b[j];

    // ---- product state r_k (redundant per lane of the same sample) -------
    float cz[4], sz[4];
    #pragma unroll
    for (int j = 0; j < 4; ++j) sincosf(0.5f * z[j], &sz[j], &cz[j]);
    float a01[4] = {cz[0]*cz[1], cz[0]*sz[1], sz[0]*cz[1], sz[0]*sz[1]};
    float a23[4] = {cz[2]*cz[3], cz[2]*sz[3], sz[2]*cz[3], sz[2]*sz[3]};
    float rv[16];
    #pragma unroll
    for (int k = 0; k < 16; ++k) rv[k] = a01[k >> 2] * a23[k & 3];

    // ---- matvec row i = cell; prob; partial classifier -------------------
    float ar = 0.f, ai = 0.f;
    #pragma unroll
    for (int k = 0; k < 16; ++k) {
        ar += sVr[cell * 17 + k] * rv[k];
        ai += sVi[cell * 17 + k] * rv[k];
    }
    const float prob = ar * ar + ai * ai;
    float out[4];
    #pragma unroll
    for (int j = 0; j < 4; ++j) out[j] = sW2[j * 17 + cell] * prob;
    #pragma unroll
    for (int m = 1; m <= 8; m <<= 1) {
        #pragma unroll
        for (int j = 0; j < 4; ++j) out[j] += __shfl_xor(out[j], m, 64);
    }
    #pragma unroll
    for (int j = 0; j < 4; ++j) out[j] += cls_b[j];

    if (cell == 0)
        ((float4*)preBN)[s0 + s] = make_float4(out[0], out[1], out[2], out[3]);

    // ---- BN statistics: one contribution per sample (cell==0 lanes) ------
    const float w = (cell == 0) ? 1.f : 0.f;
    float v8[8] = {out[0]*w, out[1]*w, out[2]*w, out[3]*w,
                   out[0]*out[0]*w, out[1]*out[1]*w, out[2]*out[2]*w, out[3]*out[3]*w};
    #pragma unroll
    for (int m = 0; m < 8; ++m) {
        v8[m] += __shfl_down(v8[m], 32, 64);
        v8[m] += __shfl_down(v8[m], 16, 64);
    }
    const int wave = tid >> 6, lane = tid & 63;
    if (lane == 0) {
        #pragma unroll
        for (int m = 0; m < 8; ++m) red[wave][m] = v8[m];
    }
    __syncthreads();
    if (tid < 8)
        atomicAdd(&sums[tid], red[0][tid] + red[1][tid] + red[2][tid] + red[3][tid]);
}

// ---- batch-norm (training mode, biased var) in place ----------------------
__global__ __launch_bounds__(256) void bn_kernel(
    const float* __restrict__ sums,
    const float* __restrict__ gamma, const float* __restrict__ beta,
    float* __restrict__ out)
{
    int s = blockIdx.x * 256 + threadIdx.x;
    const float invB = 1.f / (float)BTOT;
    float4 v = ((const float4*)out)[s];
    float o[4] = {v.x, v.y, v.z, v.w};
    #pragma unroll
    for (int j = 0; j < 4; ++j) {
        float mu   = sums[j] * invB;
        float var  = sums[4 + j] * invB - mu * mu;
        float rstd = rsqrtf(var + 1e-5f);
        o[j] = (o[j] - mu) * rstd * gamma[j] + beta[j];
    }
    ((float4*)out)[s] = make_float4(o[0], o[1], o[2], o[3]);
}

extern "C" void kernel_launch(void* const* d_in, const int* in_sizes, int n_in,
                              void* d_out, int out_size, void* d_ws, size_t ws_size,
                              hipStream_t stream)
{
    const float* x        = (const float*)d_in[0];
    const float* enc_w    = (const float*)d_in[1];
    const float* enc_b    = (const float*)d_in[2];
    const float* qparams  = (const float*)d_in[3];
    const float* cls_w    = (const float*)d_in[4];
    const float* cls_b    = (const float*)d_in[5];
    const float* bn_gamma = (const float*)d_in[6];
    const float* bn_beta  = (const float*)d_in[7];

    float* sums = (float*)d_ws;          // 8 floats (atomic accumulators)
    float* outp = (float*)d_out;         // pre-BN scratch == final out

    hipMemsetAsync(sums, 0, 8 * sizeof(float), stream);
    fused_kernel<<<BTOT / SPB, 256, 0, stream>>>(x, enc_w, enc_b, qparams,
                                                 cls_w, cls_b, outp, sums);
    bn_kernel<<<128, 256, 0, stream>>>(sums, bn_gamma, bn_beta, outp);
}

// Round 4
// 182.403 us; speedup vs baseline: 1.3110x; 1.3110x over previous
//
#include <hip/hip_runtime.h>
#include <math.h>

// ---------------------------------------------------------------------------
// QFCModel fused: avgpool(6) -> linear(16->4) -> 4-qubit circuit -> linear -> BN
//
// Circuit collapse: state = U_var @ (RX(z0)⊗..⊗RX(z3))|0>
//   amp_k = (-i)^popcount(k) * r_k, r real product of cos/sin(z/2)
//   V = U_var * diag((-i)^popc)  -> probs_i = (Vr r)_i^2 + (Vi r)_i^2
//   out_j = cls_b[j] + sum_i W2[j,i] probs_i, W2[j,i] = sum_w cls_w[j,w]*sign_w(i)
//
// R4: prep hoisted OUT of the per-block path (R3's 121 µs was ~90% the
// 2048x-replicated prep whose un-unrolled dynamic-indexed pr[]/pi[] spilled
// to scratch). prep_kernel runs once (1 block, forced full unroll, registers
// only), emits Vr/Vi/W2 + zeroed BN accumulators to ws. fused_kernel copies
// them to stride-17 LDS (conflict-free) and keeps R3's coalesced staging.
// ---------------------------------------------------------------------------

#define BTOT 32768
#define SPB  16           // samples per block
#define SSTR 676          // LDS floats per sample (672 used; 676%32=4 skew)

// ---- kernel 1: build V (Vr/Vi, row-major i*16+k), W2, zero sums ----------
__global__ __launch_bounds__(64) void prep_kernel(
    const float* __restrict__ qparams, const float* __restrict__ cls_w,
    float* __restrict__ prep)   // [0:256)=Vr, [256:512)=Vi, [512:576)=W2, [576:584)=sums
{
    const int t = threadIdx.x;
    if (t < 8) prep[576 + t] = 0.f;                    // BN accumulators
    {   // W2[j][i] = sum_w cls_w[j][w] * sign_w(i)
        int j = t >> 4, i = t & 15;
        float acc = 0.f;
        #pragma unroll
        for (int w = 0; w < 4; ++w)
            acc += cls_w[j * 4 + w] * ((i & (8 >> w)) ? -1.f : 1.f);
        prep[512 + j * 16 + i] = acc;
    }
    if (t < 16) {
        // simulate variational layers on basis state e_t -> column t of U
        float pr[16], pi[16];
        #pragma unroll
        for (int i = 0; i < 16; ++i) { pr[i] = (i == t) ? 1.f : 0.f; pi[i] = 0.f; }
        #pragma unroll
        for (int layer = 0; layer < 3; ++layer) {
            #pragma unroll
            for (int w = 0; w < 4; ++w) {
                const float* qp = qparams + (layer * 4 + w) * 3;
                float phi = qp[0], th = qp[1], om = qp[2];
                float c, s, ca, sa, cd, sd;
                __sincosf(0.5f * th, &s, &c);
                __sincosf(0.5f * (phi + om), &sa, &ca);
                __sincosf(0.5f * (phi - om), &sd, &cd);
                float u00r =  c * ca, u00i = -c * sa;
                float u01r = -s * cd, u01i = -s * sd;
                float u10r =  s * cd, u10i = -s * sd;
                float u11r =  c * ca, u11i =  c * sa;
                const int m = 8 >> w;   // wire 0 = MSB
                #pragma unroll
                for (int idx = 0; idx < 16; ++idx) {
                    if (idx & m) continue;
                    const int i1 = idx | m;
                    float ar = pr[idx], ai = pi[idx], br = pr[i1], bi = pi[i1];
                    pr[idx] = u00r*ar - u00i*ai + u01r*br - u01i*bi;
                    pi[idx] = u00r*ai + u00i*ar + u01r*bi + u01i*br;
                    pr[i1]  = u10r*ar - u10i*ai + u11r*br - u11i*bi;
                    pi[i1]  = u10r*ai + u10i*ar + u11r*bi + u11i*br;
                }
            }
            #pragma unroll
            for (int w = 0; w < 3; ++w) {  // CNOT ladder (register renames)
                const int mc = 8 >> w, mt = 8 >> (w + 1);
                #pragma unroll
                for (int idx = 0; idx < 16; ++idx) {
                    if ((idx & mc) && !(idx & mt)) {
                        const int i1 = idx | mt;
                        float tr = pr[idx], ti = pi[idx];
                        pr[idx] = pr[i1]; pi[idx] = pi[i1];
                        pr[i1] = tr;      pi[i1] = ti;
                    }
                }
            }
        }
        // fold (-i)^popcount(column t)
        const int p = __popc(t) & 3;
        #pragma unroll
        for (int i = 0; i < 16; ++i) {
            float re = pr[i], im = pi[i], vr, vi;
            if (p == 0)      { vr = re;  vi = im;  }
            else if (p == 1) { vr = im;  vi = -re; }
            else if (p == 2) { vr = -re; vi = -im; }
            else             { vr = -im; vi = re;  }
            prep[i * 16 + t]       = vr;
            prep[256 + i * 16 + t] = vi;
        }
    }
}

// ---- kernel 2: stage->pool->encode->circuit->classify + BN stats ----------
__global__ __launch_bounds__(256) void fused_kernel(
    const float* __restrict__ x,
    const float* __restrict__ enc_w, const float* __restrict__ enc_b,
    const float* __restrict__ prep, const float* __restrict__ cls_b,
    float* __restrict__ preBN, float* __restrict__ sums)
{
    __shared__ float sx[SPB * SSTR];     // 43264 B staged image rows 0..23
    __shared__ float sVr[16 * 17];       // stride 17: 17k mod 32 injective
    __shared__ float sVi[16 * 17];
    __shared__ float sW2[4 * 17];
    __shared__ float red[4][8];

    const int tid = threadIdx.x;

    // ---- copy prep constants into banked LDS (3 coalesced rounds) --------
    #pragma unroll
    for (int g0 = 0; g0 < 576; g0 += 256) {
        int g = g0 + tid;
        if (g < 576) {
            float v = prep[g];
            int row = (g >> 4) & 15, col = g & 15;
            if (g < 256)      sVr[row * 17 + col] = v;
            else if (g < 512) sVi[row * 17 + col] = v;
            else              sW2[(g - 512) / 16 * 17 + col] = v;
        }
    }

    // ---- stage rows 0..23 of 16 samples, fully coalesced float4 ----------
    const int s0 = blockIdx.x * SPB;
    const float4* xb = (const float4*)x;
    #pragma unroll
    for (int it = 0; it < 11; ++it) {
        int gid = it * 256 + tid;
        if (gid < SPB * 168) {
            int c = gid / 168;          // sample within block
            int o = gid - c * 168;      // float4 offset within rows 0..23
            float4 v = xb[(size_t)(s0 + c) * 196 + o];
            *(float4*)&sx[c * SSTR + o * 4] = v;
        }
    }
    __syncthreads();

    // ---- pool: thread (s, cell) sums its 6x6 window from LDS -------------
    const int s = tid >> 4, cell = tid & 15;
    const int cr = cell >> 2, cc = cell & 3;
    const float* sb = &sx[s * SSTR + cr * 6 * 28 + cc * 6];
    float sum = 0.f;
    #pragma unroll
    for (int r = 0; r < 6; ++r) {
        const float* rp = sb + r * 28;
        sum += (rp[0] + rp[1]) + (rp[2] + rp[3]) + (rp[4] + rp[5]);
    }
    const float pv = sum * (1.f / 36.f);

    // ---- encode: z_j = sum_cells enc_w[j][cell]*pv, 16-lane xor-reduce ---
    float z[4];
    #pragma unroll
    for (int j = 0; j < 4; ++j) z[j] = enc_w[j * 16 + cell] * pv;
    #pragma unroll
    for (int m = 1; m <= 8; m <<= 1) {
        #pragma unroll
        for (int j = 0; j < 4; ++j) z[j] += __shfl_xor(z[j], m, 64);
    }
    #pragma unroll
    for (int j = 0; j < 4; ++j) z[j] += enc_b[j];

    // ---- product state r_k ------------------------------------------------
    float cz[4], sz[4];
    #pragma unroll
    for (int j = 0; j < 4; ++j) __sincosf(0.5f * z[j], &sz[j], &cz[j]);
    float a01[4] = {cz[0]*cz[1], cz[0]*sz[1], sz[0]*cz[1], sz[0]*sz[1]};
    float a23[4] = {cz[2]*cz[3], cz[2]*sz[3], sz[2]*cz[3], sz[2]*sz[3]};
    float rv[16];
    #pragma unroll
    for (int k = 0; k < 16; ++k) rv[k] = a01[k >> 2] * a23[k & 3];

    // ---- matvec row i = cell; prob; partial classifier --------------------
    float ar = 0.f, ai = 0.f;
    #pragma unroll
    for (int k = 0; k < 16; ++k) {
        ar += sVr[cell * 17 + k] * rv[k];
        ai += sVi[cell * 17 + k] * rv[k];
    }
    const float prob = ar * ar + ai * ai;
    float out[4];
    #pragma unroll
    for (int j = 0; j < 4; ++j) out[j] = sW2[j * 17 + cell] * prob;
    #pragma unroll
    for (int m = 1; m <= 8; m <<= 1) {
        #pragma unroll
        for (int j = 0; j < 4; ++j) out[j] += __shfl_xor(out[j], m, 64);
    }
    #pragma unroll
    for (int j = 0; j < 4; ++j) out[j] += cls_b[j];

    if (cell == 0)
        ((float4*)preBN)[s0 + s] = make_float4(out[0], out[1], out[2], out[3]);

    // ---- BN statistics: one contribution per sample (cell==0 lanes) -------
    const float w = (cell == 0) ? 1.f : 0.f;
    float v8[8] = {out[0]*w, out[1]*w, out[2]*w, out[3]*w,
                   out[0]*out[0]*w, out[1]*out[1]*w, out[2]*out[2]*w, out[3]*out[3]*w};
    #pragma unroll
    for (int m = 0; m < 8; ++m) {
        v8[m] += __shfl_down(v8[m], 32, 64);
        v8[m] += __shfl_down(v8[m], 16, 64);
    }
    const int wave = tid >> 6, lane = tid & 63;
    if (lane == 0) {
        #pragma unroll
        for (int m = 0; m < 8; ++m) red[wave][m] = v8[m];
    }
    __syncthreads();
    if (tid < 8)
        atomicAdd(&sums[tid], red[0][tid] + red[1][tid] + red[2][tid] + red[3][tid]);
}

// ---- kernel 3: batch-norm (training mode, biased var) in place ------------
__global__ __launch_bounds__(256) void bn_kernel(
    const float* __restrict__ sums,
    const float* __restrict__ gamma, const float* __restrict__ beta,
    float* __restrict__ out)
{
    int s = blockIdx.x * 256 + threadIdx.x;
    const float invB = 1.f / (float)BTOT;
    float4 v = ((const float4*)out)[s];
    float o[4] = {v.x, v.y, v.z, v.w};
    #pragma unroll
    for (int j = 0; j < 4; ++j) {
        float mu   = sums[j] * invB;
        float var  = sums[4 + j] * invB - mu * mu;
        float rstd = rsqrtf(var + 1e-5f);
        o[j] = (o[j] - mu) * rstd * gamma[j] + beta[j];
    }
    ((float4*)out)[s] = make_float4(o[0], o[1], o[2], o[3]);
}

extern "C" void kernel_launch(void* const* d_in, const int* in_sizes, int n_in,
                              void* d_out, int out_size, void* d_ws, size_t ws_size,
                              hipStream_t stream)
{
    const float* x        = (const float*)d_in[0];
    const float* enc_w    = (const float*)d_in[1];
    const float* enc_b    = (const float*)d_in[2];
    const float* qparams  = (const float*)d_in[3];
    const float* cls_w    = (const float*)d_in[4];
    const float* cls_b    = (const float*)d_in[5];
    const float* bn_gamma = (const float*)d_in[6];
    const float* bn_beta  = (const float*)d_in[7];

    float* prep = (float*)d_ws;          // 576 floats V/W2 + 8 accumulators
    float* sums = prep + 576;
    float* outp = (float*)d_out;         // pre-BN scratch == final out

    prep_kernel<<<1, 64, 0, stream>>>(qparams, cls_w, prep);
    fused_kernel<<<BTOT / SPB, 256, 0, stream>>>(x, enc_w, enc_b, prep, cls_b,
                                                 outp, sums);
    bn_kernel<<<128, 256, 0, stream>>>(sums, bn_gamma, bn_beta, outp);
}

// Round 5
// 177.131 us; speedup vs baseline: 1.3500x; 1.0298x over previous
//
#include <hip/hip_runtime.h>
#include <math.h>

// ---------------------------------------------------------------------------
// QFCModel fused: avgpool(6) -> linear(16->4) -> 4-qubit circuit -> linear -> BN
//
// Circuit collapse: state = U_var @ (RX(z0)⊗..⊗RX(z3))|0>
//   amp_k = (-i)^popcount(k) * r_k, r real product of cos/sin(z/2)
//   V = U_var * diag((-i)^popc)  -> probs_i = (Vr r)_i^2 + (Vi r)_i^2
//   out_j = cls_b[j] + sum_i W2[j,i] probs_i, W2[j,i] = sum_w cls_w[j,w]*sign_w(i)
//
// R5: BN stats via per-block partial STORES + redundant reduction in bn_kernel.
// R4's fused (~50 us) was throttled by 2048 blocks atomicAdd-ing the same
// 32B line (cross-XCD same-line serialization ~40 us; every block's endpgm
// waits on its atomic). Now zero contention; memset node gone too.
// ---------------------------------------------------------------------------

#define BTOT 32768
#define SPB  16           // samples per block
#define NBLK (BTOT / SPB) // 2048 fused blocks
#define SSTR 676          // LDS floats per sample (672 used; 676%32=4 skew)

// ---- kernel 1: build V (Vr/Vi, row-major i*16+k) and W2 -------------------
__global__ __launch_bounds__(64) void prep_kernel(
    const float* __restrict__ qparams, const float* __restrict__ cls_w,
    float* __restrict__ prep)   // [0:256)=Vr, [256:512)=Vi, [512:576)=W2
{
    const int t = threadIdx.x;
    {   // W2[j][i] = sum_w cls_w[j][w] * sign_w(i)
        int j = t >> 4, i = t & 15;
        float acc = 0.f;
        #pragma unroll
        for (int w = 0; w < 4; ++w)
            acc += cls_w[j * 4 + w] * ((i & (8 >> w)) ? -1.f : 1.f);
        prep[512 + j * 16 + i] = acc;
    }
    if (t < 16) {
        // simulate variational layers on basis state e_t -> column t of U
        float pr[16], pi[16];
        #pragma unroll
        for (int i = 0; i < 16; ++i) { pr[i] = (i == t) ? 1.f : 0.f; pi[i] = 0.f; }
        #pragma unroll
        for (int layer = 0; layer < 3; ++layer) {
            #pragma unroll
            for (int w = 0; w < 4; ++w) {
                const float* qp = qparams + (layer * 4 + w) * 3;
                float phi = qp[0], th = qp[1], om = qp[2];
                float c, s, ca, sa, cd, sd;
                __sincosf(0.5f * th, &s, &c);
                __sincosf(0.5f * (phi + om), &sa, &ca);
                __sincosf(0.5f * (phi - om), &sd, &cd);
                float u00r =  c * ca, u00i = -c * sa;
                float u01r = -s * cd, u01i = -s * sd;
                float u10r =  s * cd, u10i = -s * sd;
                float u11r =  c * ca, u11i =  c * sa;
                const int m = 8 >> w;   // wire 0 = MSB
                #pragma unroll
                for (int idx = 0; idx < 16; ++idx) {
                    if (idx & m) continue;
                    const int i1 = idx | m;
                    float ar = pr[idx], ai = pi[idx], br = pr[i1], bi = pi[i1];
                    pr[idx] = u00r*ar - u00i*ai + u01r*br - u01i*bi;
                    pi[idx] = u00r*ai + u00i*ar + u01r*bi + u01i*br;
                    pr[i1]  = u10r*ar - u10i*ai + u11r*br - u11i*bi;
                    pi[i1]  = u10r*ai + u10i*ar + u11r*bi + u11i*br;
                }
            }
            #pragma unroll
            for (int w = 0; w < 3; ++w) {  // CNOT ladder (register renames)
                const int mc = 8 >> w, mt = 8 >> (w + 1);
                #pragma unroll
                for (int idx = 0; idx < 16; ++idx) {
                    if ((idx & mc) && !(idx & mt)) {
                        const int i1 = idx | mt;
                        float tr = pr[idx], ti = pi[idx];
                        pr[idx] = pr[i1]; pi[idx] = pi[i1];
                        pr[i1] = tr;      pi[i1] = ti;
                    }
                }
            }
        }
        // fold (-i)^popcount(column t)
        const int p = __popc(t) & 3;
        #pragma unroll
        for (int i = 0; i < 16; ++i) {
            float re = pr[i], im = pi[i], vr, vi;
            if (p == 0)      { vr = re;  vi = im;  }
            else if (p == 1) { vr = im;  vi = -re; }
            else if (p == 2) { vr = -re; vi = -im; }
            else             { vr = -im; vi = re;  }
            prep[i * 16 + t]       = vr;
            prep[256 + i * 16 + t] = vi;
        }
    }
}

// ---- kernel 2: stage->pool->encode->circuit->classify + partial BN stats --
__global__ __launch_bounds__(256) void fused_kernel(
    const float* __restrict__ x,
    const float* __restrict__ enc_w, const float* __restrict__ enc_b,
    const float* __restrict__ prep, const float* __restrict__ cls_b,
    float* __restrict__ preBN, float* __restrict__ partials)
{
    __shared__ float sx[SPB * SSTR];     // 43264 B staged image rows 0..23
    __shared__ float sVr[16 * 17];       // stride 17: 17k mod 32 injective
    __shared__ float sVi[16 * 17];
    __shared__ float sW2[4 * 17];
    __shared__ float red[4][8];

    const int tid = threadIdx.x;

    // ---- copy prep constants into banked LDS (3 coalesced rounds) --------
    #pragma unroll
    for (int g0 = 0; g0 < 576; g0 += 256) {
        int g = g0 + tid;
        if (g < 576) {
            float v = prep[g];
            int row = (g >> 4) & 15, col = g & 15;
            if (g < 256)      sVr[row * 17 + col] = v;
            else if (g < 512) sVi[row * 17 + col] = v;
            else              sW2[(g - 512) / 16 * 17 + col] = v;
        }
    }

    // ---- stage rows 0..23 of 16 samples, fully coalesced float4 ----------
    const int s0 = blockIdx.x * SPB;
    const float4* xb = (const float4*)x;
    #pragma unroll
    for (int it = 0; it < 11; ++it) {
        int gid = it * 256 + tid;
        if (gid < SPB * 168) {
            int c = gid / 168;          // sample within block
            int o = gid - c * 168;      // float4 offset within rows 0..23
            float4 v = xb[(size_t)(s0 + c) * 196 + o];
            *(float4*)&sx[c * SSTR + o * 4] = v;
        }
    }
    __syncthreads();

    // ---- pool: thread (s, cell) sums its 6x6 window from LDS -------------
    const int s = tid >> 4, cell = tid & 15;
    const int cr = cell >> 2, cc = cell & 3;
    const float* sb = &sx[s * SSTR + cr * 6 * 28 + cc * 6];
    float sum = 0.f;
    #pragma unroll
    for (int r = 0; r < 6; ++r) {
        const float* rp = sb + r * 28;
        sum += (rp[0] + rp[1]) + (rp[2] + rp[3]) + (rp[4] + rp[5]);
    }
    const float pv = sum * (1.f / 36.f);

    // ---- encode: z_j = sum_cells enc_w[j][cell]*pv, 16-lane xor-reduce ---
    float z[4];
    #pragma unroll
    for (int j = 0; j < 4; ++j) z[j] = enc_w[j * 16 + cell] * pv;
    #pragma unroll
    for (int m = 1; m <= 8; m <<= 1) {
        #pragma unroll
        for (int j = 0; j < 4; ++j) z[j] += __shfl_xor(z[j], m, 64);
    }
    #pragma unroll
    for (int j = 0; j < 4; ++j) z[j] += enc_b[j];

    // ---- product state r_k ------------------------------------------------
    float cz[4], sz[4];
    #pragma unroll
    for (int j = 0; j < 4; ++j) __sincosf(0.5f * z[j], &sz[j], &cz[j]);
    float a01[4] = {cz[0]*cz[1], cz[0]*sz[1], sz[0]*cz[1], sz[0]*sz[1]};
    float a23[4] = {cz[2]*cz[3], cz[2]*sz[3], sz[2]*cz[3], sz[2]*sz[3]};
    float rv[16];
    #pragma unroll
    for (int k = 0; k < 16; ++k) rv[k] = a01[k >> 2] * a23[k & 3];

    // ---- matvec row i = cell; prob; partial classifier --------------------
    float ar = 0.f, ai = 0.f;
    #pragma unroll
    for (int k = 0; k < 16; ++k) {
        ar += sVr[cell * 17 + k] * rv[k];
        ai += sVi[cell * 17 + k] * rv[k];
    }
    const float prob = ar * ar + ai * ai;
    float out[4];
    #pragma unroll
    for (int j = 0; j < 4; ++j) out[j] = sW2[j * 17 + cell] * prob;
    #pragma unroll
    for (int m = 1; m <= 8; m <<= 1) {
        #pragma unroll
        for (int j = 0; j < 4; ++j) out[j] += __shfl_xor(out[j], m, 64);
    }
    #pragma unroll
    for (int j = 0; j < 4; ++j) out[j] += cls_b[j];

    if (cell == 0)
        ((float4*)preBN)[s0 + s] = make_float4(out[0], out[1], out[2], out[3]);

    // ---- BN partials: one contribution per sample (cell==0 lanes) ---------
    const float w = (cell == 0) ? 1.f : 0.f;
    float v8[8] = {out[0]*w, out[1]*w, out[2]*w, out[3]*w,
                   out[0]*out[0]*w, out[1]*out[1]*w, out[2]*out[2]*w, out[3]*out[3]*w};
    #pragma unroll
    for (int m = 0; m < 8; ++m) {
        v8[m] += __shfl_down(v8[m], 32, 64);
        v8[m] += __shfl_down(v8[m], 16, 64);
    }
    const int wave = tid >> 6, lane = tid & 63;
    if (lane == 0) {
        #pragma unroll
        for (int m = 0; m < 8; ++m) red[wave][m] = v8[m];
    }
    __syncthreads();
    // plain coalesced store to a private slot — NO atomics, no contention
    if (tid < 8)
        partials[blockIdx.x * 8 + tid] =
            red[0][tid] + red[1][tid] + red[2][tid] + red[3][tid];
}

// ---- kernel 3: reduce partials (redundantly per block) + batch-norm -------
__global__ __launch_bounds__(256) void bn_kernel(
    const float* __restrict__ partials,
    const float* __restrict__ gamma, const float* __restrict__ beta,
    float* __restrict__ out)
{
    const int tid = threadIdx.x;
    float acc[8] = {0, 0, 0, 0, 0, 0, 0, 0};
    const float4* p4 = (const float4*)partials;
    #pragma unroll
    for (int it = 0; it < NBLK / 256; ++it) {
        int b = it * 256 + tid;
        float4 a = p4[b * 2], c = p4[b * 2 + 1];
        acc[0] += a.x; acc[1] += a.y; acc[2] += a.z; acc[3] += a.w;
        acc[4] += c.x; acc[5] += c.y; acc[6] += c.z; acc[7] += c.w;
    }
    #pragma unroll
    for (int off = 32; off >= 1; off >>= 1) {
        #pragma unroll
        for (int m = 0; m < 8; ++m) acc[m] += __shfl_xor(acc[m], off, 64);
    }
    __shared__ float red[4][8];
    const int wave = tid >> 6, lane = tid & 63;
    if (lane == 0) {
        #pragma unroll
        for (int m = 0; m < 8; ++m) red[wave][m] = acc[m];
    }
    __syncthreads();
    float sums[8];
    #pragma unroll
    for (int m = 0; m < 8; ++m)
        sums[m] = red[0][m] + red[1][m] + red[2][m] + red[3][m];

    const int s = blockIdx.x * 256 + tid;
    const float invB = 1.f / (float)BTOT;
    float4 v = ((const float4*)out)[s];
    float o[4] = {v.x, v.y, v.z, v.w};
    #pragma unroll
    for (int j = 0; j < 4; ++j) {
        float mu   = sums[j] * invB;
        float var  = sums[4 + j] * invB - mu * mu;
        float rstd = rsqrtf(var + 1e-5f);
        o[j] = (o[j] - mu) * rstd * gamma[j] + beta[j];
    }
    ((float4*)out)[s] = make_float4(o[0], o[1], o[2], o[3]);
}

extern "C" void kernel_launch(void* const* d_in, const int* in_sizes, int n_in,
                              void* d_out, int out_size, void* d_ws, size_t ws_size,
                              hipStream_t stream)
{
    const float* x        = (const float*)d_in[0];
    const float* enc_w    = (const float*)d_in[1];
    const float* enc_b    = (const float*)d_in[2];
    const float* qparams  = (const float*)d_in[3];
    const float* cls_w    = (const float*)d_in[4];
    const float* cls_b    = (const float*)d_in[5];
    const float* bn_gamma = (const float*)d_in[6];
    const float* bn_beta  = (const float*)d_in[7];

    float* prep     = (float*)d_ws;      // 576 floats (V, W2)
    float* partials = prep + 576;        // 2048 * 8 floats (written, no init)
    float* outp     = (float*)d_out;     // pre-BN scratch == final out

    prep_kernel<<<1, 64, 0, stream>>>(qparams, cls_w, prep);
    fused_kernel<<<NBLK, 256, 0, stream>>>(x, enc_w, enc_b, prep, cls_b,
                                           outp, partials);
    bn_kernel<<<128, 256, 0, stream>>>(partials, bn_gamma, bn_beta, outp);
}

// Round 6
// 175.307 us; speedup vs baseline: 1.3641x; 1.0104x over previous
//
#include <hip/hip_runtime.h>
#include <math.h>

// ---------------------------------------------------------------------------
// QFCModel fused: avgpool(6) -> linear(16->4) -> 4-qubit circuit -> linear -> BN
//
// Circuit collapse: state = U_var @ (RX(z0)⊗..⊗RX(z3))|0>
//   amp_k = (-i)^popcount(k) * r_k, r real product of cos/sin(z/2)
//   V = U_var * diag((-i)^popc)  -> probs_i = (Vr r)_i^2 + (Vi r)_i^2
//   out_j = cls_b[j] + sum_i W2[j,i] probs_i, W2[j,i] = sum_w cls_w[j,w]*sign_w(i)
//
// R6: staging via __builtin_amdgcn_global_load_lds width=16 (async DMA, no
// VGPR round-trip; compiler never auto-emits it). R5's fused (~50 us vs
// ~15 us model) kept VGPR=68 => the 11 float4 staging loads were NOT hoisted
// (44 VGPRs needed); per-iteration load->wait->ds_write underdrove the
// memory pipe. DMA constraint: LDS dest = wave-uniform base + lane*16
// => SSTR drops 676->672 (addresses exactly gid*16). Pool-phase LDS reads
// stay 4-way/16-bank (~1.58x, negligible); V keeps stride-17 (conflict-free).
// ---------------------------------------------------------------------------

#define BTOT 32768
#define SPB  16           // samples per block
#define NBLK (BTOT / SPB) // 2048 fused blocks
#define SSTR 672          // LDS floats per sample — NO pad (DMA lane*16 rule)

// ---- kernel 1: build V (Vr/Vi, row-major i*16+k) and W2 -------------------
__global__ __launch_bounds__(64) void prep_kernel(
    const float* __restrict__ qparams, const float* __restrict__ cls_w,
    float* __restrict__ prep)   // [0:256)=Vr, [256:512)=Vi, [512:576)=W2
{
    const int t = threadIdx.x;
    {   // W2[j][i] = sum_w cls_w[j][w] * sign_w(i)
        int j = t >> 4, i = t & 15;
        float acc = 0.f;
        #pragma unroll
        for (int w = 0; w < 4; ++w)
            acc += cls_w[j * 4 + w] * ((i & (8 >> w)) ? -1.f : 1.f);
        prep[512 + j * 16 + i] = acc;
    }
    if (t < 16) {
        // simulate variational layers on basis state e_t -> column t of U
        float pr[16], pi[16];
        #pragma unroll
        for (int i = 0; i < 16; ++i) { pr[i] = (i == t) ? 1.f : 0.f; pi[i] = 0.f; }
        #pragma unroll
        for (int layer = 0; layer < 3; ++layer) {
            #pragma unroll
            for (int w = 0; w < 4; ++w) {
                const float* qp = qparams + (layer * 4 + w) * 3;
                float phi = qp[0], th = qp[1], om = qp[2];
                float c, s, ca, sa, cd, sd;
                __sincosf(0.5f * th, &s, &c);
                __sincosf(0.5f * (phi + om), &sa, &ca);
                __sincosf(0.5f * (phi - om), &sd, &cd);
                float u00r =  c * ca, u00i = -c * sa;
                float u01r = -s * cd, u01i = -s * sd;
                float u10r =  s * cd, u10i = -s * sd;
                float u11r =  c * ca, u11i =  c * sa;
                const int m = 8 >> w;   // wire 0 = MSB
                #pragma unroll
                for (int idx = 0; idx < 16; ++idx) {
                    if (idx & m) continue;
                    const int i1 = idx | m;
                    float ar = pr[idx], ai = pi[idx], br = pr[i1], bi = pi[i1];
                    pr[idx] = u00r*ar - u00i*ai + u01r*br - u01i*bi;
                    pi[idx] = u00r*ai + u00i*ar + u01r*bi + u01i*br;
                    pr[i1]  = u10r*ar - u10i*ai + u11r*br - u11i*bi;
                    pi[i1]  = u10r*ai + u10i*ar + u11r*bi + u11i*br;
                }
            }
            #pragma unroll
            for (int w = 0; w < 3; ++w) {  // CNOT ladder (register renames)
                const int mc = 8 >> w, mt = 8 >> (w + 1);
                #pragma unroll
                for (int idx = 0; idx < 16; ++idx) {
                    if ((idx & mc) && !(idx & mt)) {
                        const int i1 = idx | mt;
                        float tr = pr[idx], ti = pi[idx];
                        pr[idx] = pr[i1]; pi[idx] = pi[i1];
                        pr[i1] = tr;      pi[i1] = ti;
                    }
                }
            }
        }
        // fold (-i)^popcount(column t)
        const int p = __popc(t) & 3;
        #pragma unroll
        for (int i = 0; i < 16; ++i) {
            float re = pr[i], im = pi[i], vr, vi;
            if (p == 0)      { vr = re;  vi = im;  }
            else if (p == 1) { vr = im;  vi = -re; }
            else if (p == 2) { vr = -re; vi = -im; }
            else             { vr = -im; vi = re;  }
            prep[i * 16 + t]       = vr;
            prep[256 + i * 16 + t] = vi;
        }
    }
}

// ---- kernel 2: DMA-stage->pool->encode->circuit->classify + BN partials ---
__global__ __launch_bounds__(256) void fused_kernel(
    const float* __restrict__ x,
    const float* __restrict__ enc_w, const float* __restrict__ enc_b,
    const float* __restrict__ prep, const float* __restrict__ cls_b,
    float* __restrict__ preBN, float* __restrict__ partials)
{
    __shared__ float sx[SPB * SSTR];     // 43008 B staged rows 0..23, dense
    __shared__ float sVr[16 * 17];       // stride 17: 17c mod 32 injective
    __shared__ float sVi[16 * 17];
    __shared__ float sW2[4 * 17];
    __shared__ float red[4][8];

    const int tid = threadIdx.x;
    const int s0  = blockIdx.x * SPB;
    const float4* xb = (const float4*)x;

    // ---- stage rows 0..23 of 16 samples via async global->LDS DMA --------
    // gid = it*256+tid; LDS byte addr = gid*16 (dense) = wave-base + lane*16.
    // 2688 float4 total: it=0..9 all waves, it=10 only waves 0,1 (full waves).
    {
        const int waveBase = tid & ~63;            // wave-uniform
        #pragma unroll
        for (int it = 0; it < 11; ++it) {
            const int gid = it * 256 + tid;
            if (gid < SPB * 168) {
                const int c = gid / 168;           // sample within block
                const int o = gid - c * 168;       // f4 offset in rows 0..23
                const float4* gsrc = xb + (size_t)(s0 + c) * 196 + o;
                float* lbase = &sx[(size_t)(it * 256 + waveBase) * 4];
                __builtin_amdgcn_global_load_lds(
                    (const __attribute__((address_space(1))) void*)gsrc,
                    (__attribute__((address_space(3))) void*)lbase,
                    16, 0, 0);
            }
        }
    }

    // ---- copy prep constants into banked LDS (overlaps DMA) --------------
    #pragma unroll
    for (int g0 = 0; g0 < 576; g0 += 256) {
        int g = g0 + tid;
        if (g < 576) {
            float v = prep[g];
            int row = (g >> 4) & 15, col = g & 15;
            if (g < 256)      sVr[row * 17 + col] = v;
            else if (g < 512) sVi[row * 17 + col] = v;
            else              sW2[(g - 512) / 16 * 17 + col] = v;
        }
    }
    __syncthreads();   // drains vmcnt (DMA) + lgkmcnt

    // ---- pool: thread (s, cell) sums its 6x6 window from LDS -------------
    const int s = tid >> 4, cell = tid & 15;
    const int cr = cell >> 2, cc = cell & 3;
    const float* sb = &sx[s * SSTR + cr * 6 * 28 + cc * 6];
    float sum = 0.f;
    #pragma unroll
    for (int r = 0; r < 6; ++r) {
        const float* rp = sb + r * 28;
        sum += (rp[0] + rp[1]) + (rp[2] + rp[3]) + (rp[4] + rp[5]);
    }
    const float pv = sum * (1.f / 36.f);

    // ---- encode: z_j = sum_cells enc_w[j][cell]*pv, 16-lane xor-reduce ---
    float z[4];
    #pragma unroll
    for (int j = 0; j < 4; ++j) z[j] = enc_w[j * 16 + cell] * pv;
    #pragma unroll
    for (int m = 1; m <= 8; m <<= 1) {
        #pragma unroll
        for (int j = 0; j < 4; ++j) z[j] += __shfl_xor(z[j], m, 64);
    }
    #pragma unroll
    for (int j = 0; j < 4; ++j) z[j] += enc_b[j];

    // ---- product state r_k ------------------------------------------------
    float cz[4], sz[4];
    #pragma unroll
    for (int j = 0; j < 4; ++j) __sincosf(0.5f * z[j], &sz[j], &cz[j]);
    float a01[4] = {cz[0]*cz[1], cz[0]*sz[1], sz[0]*cz[1], sz[0]*sz[1]};
    float a23[4] = {cz[2]*cz[3], cz[2]*sz[3], sz[2]*cz[3], sz[2]*sz[3]};
    float rv[16];
    #pragma unroll
    for (int k = 0; k < 16; ++k) rv[k] = a01[k >> 2] * a23[k & 3];

    // ---- matvec row i = cell; prob; partial classifier --------------------
    float ar = 0.f, ai = 0.f;
    #pragma unroll
    for (int k = 0; k < 16; ++k) {
        ar += sVr[cell * 17 + k] * rv[k];
        ai += sVi[cell * 17 + k] * rv[k];
    }
    const float prob = ar * ar + ai * ai;
    float out[4];
    #pragma unroll
    for (int j = 0; j < 4; ++j) out[j] = sW2[j * 17 + cell] * prob;
    #pragma unroll
    for (int m = 1; m <= 8; m <<= 1) {
        #pragma unroll
        for (int j = 0; j < 4; ++j) out[j] += __shfl_xor(out[j], m, 64);
    }
    #pragma unroll
    for (int j = 0; j < 4; ++j) out[j] += cls_b[j];

    if (cell == 0)
        ((float4*)preBN)[s0 + s] = make_float4(out[0], out[1], out[2], out[3]);

    // ---- BN partials: one contribution per sample (cell==0 lanes) ---------
    const float w = (cell == 0) ? 1.f : 0.f;
    float v8[8] = {out[0]*w, out[1]*w, out[2]*w, out[3]*w,
                   out[0]*out[0]*w, out[1]*out[1]*w, out[2]*out[2]*w, out[3]*out[3]*w};
    #pragma unroll
    for (int m = 0; m < 8; ++m) {
        v8[m] += __shfl_down(v8[m], 32, 64);
        v8[m] += __shfl_down(v8[m], 16, 64);
    }
    const int wave = tid >> 6, lane = tid & 63;
    if (lane == 0) {
        #pragma unroll
        for (int m = 0; m < 8; ++m) red[wave][m] = v8[m];
    }
    __syncthreads();
    // plain coalesced store to a private slot — no atomics
    if (tid < 8)
        partials[blockIdx.x * 8 + tid] =
            red[0][tid] + red[1][tid] + red[2][tid] + red[3][tid];
}

// ---- kernel 3: reduce partials (redundantly per block) + batch-norm -------
__global__ __launch_bounds__(256) void bn_kernel(
    const float* __restrict__ partials,
    const float* __restrict__ gamma, const float* __restrict__ beta,
    float* __restrict__ out)
{
    const int tid = threadIdx.x;
    float acc[8] = {0, 0, 0, 0, 0, 0, 0, 0};
    const float4* p4 = (const float4*)partials;
    #pragma unroll
    for (int it = 0; it < NBLK / 256; ++it) {
        int b = it * 256 + tid;
        float4 a = p4[b * 2], c = p4[b * 2 + 1];
        acc[0] += a.x; acc[1] += a.y; acc[2] += a.z; acc[3] += a.w;
        acc[4] += c.x; acc[5] += c.y; acc[6] += c.z; acc[7] += c.w;
    }
    #pragma unroll
    for (int off = 32; off >= 1; off >>= 1) {
        #pragma unroll
        for (int m = 0; m < 8; ++m) acc[m] += __shfl_xor(acc[m], off, 64);
    }
    __shared__ float red[4][8];
    const int wave = tid >> 6, lane = tid & 63;
    if (lane == 0) {
        #pragma unroll
        for (int m = 0; m < 8; ++m) red[wave][m] = acc[m];
    }
    __syncthreads();
    float sums[8];
    #pragma unroll
    for (int m = 0; m < 8; ++m)
        sums[m] = red[0][m] + red[1][m] + red[2][m] + red[3][m];

    const int s = blockIdx.x * 256 + tid;
    const float invB = 1.f / (float)BTOT;
    float4 v = ((const float4*)out)[s];
    float o[4] = {v.x, v.y, v.z, v.w};
    #pragma unroll
    for (int j = 0; j < 4; ++j) {
        float mu   = sums[j] * invB;
        float var  = sums[4 + j] * invB - mu * mu;
        float rstd = rsqrtf(var + 1e-5f);
        o[j] = (o[j] - mu) * rstd * gamma[j] + beta[j];
    }
    ((float4*)out)[s] = make_float4(o[0], o[1], o[2], o[3]);
}

extern "C" void kernel_launch(void* const* d_in, const int* in_sizes, int n_in,
                              void* d_out, int out_size, void* d_ws, size_t ws_size,
                              hipStream_t stream)
{
    const float* x        = (const float*)d_in[0];
    const float* enc_w    = (const float*)d_in[1];
    const float* enc_b    = (const float*)d_in[2];
    const float* qparams  = (const float*)d_in[3];
    const float* cls_w    = (const float*)d_in[4];
    const float* cls_b    = (const float*)d_in[5];
    const float* bn_gamma = (const float*)d_in[6];
    const float* bn_beta  = (const float*)d_in[7];

    float* prep     = (float*)d_ws;      // 576 floats (V, W2)
    float* partials = prep + 576;        // 2048 * 8 floats (written, no init)
    float* outp     = (float*)d_out;     // pre-BN scratch == final out

    prep_kernel<<<1, 64, 0, stream>>>(qparams, cls_w, prep);
    fused_kernel<<<NBLK, 256, 0, stream>>>(x, enc_w, enc_b, prep, cls_b,
                                           outp, partials);
    bn_kernel<<<128, 256, 0, stream>>>(partials, bn_gamma, bn_beta, outp);
}

// Round 8
// 174.090 us; speedup vs baseline: 1.3736x; 1.0070x over previous
//
#include <hip/hip_runtime.h>
#include <math.h>

// ---------------------------------------------------------------------------
// QFCModel fused: avgpool(6) -> linear(16->4) -> 4-qubit circuit -> linear -> BN
//
// Circuit collapse: state = U_var @ (RX(z0)⊗..⊗RX(z3))|0>
//   amp_k = (-i)^popcount(k) * r_k, r real product of cos/sin(z/2)
//   V = U_var * diag((-i)^popc)  -> probs_i = (Vr r)_i^2 + (Vi r)_i^2
//   out_j = cls_b[j] + sum_i W2[j,i] probs_i, W2[j,i] = sum_w cls_w[j,w]*sign_w(i)
//
// R8 = R7 with the rotation-mod bug fixed: R7 computed (rr+s) "mod 6" with a
// single conditional subtract, but s goes to 15 (rr+s up to 20) => rows read
// from the wrong block-row for s>=7 (absmax 5.875). Now srot = s mod 6 first.
// R7 intent unchanged: stage only cols 0..23 (144 f4/sample, LDS 39.4 KB =>
// 4 blocks/CU, 16 waves/CU vs R6's 3/12), 9 exact DMA rounds, row-rotated
// float2 pool reads to spread banks.
// ---------------------------------------------------------------------------

#define BTOT 32768
#define SPB  16           // samples per block
#define NBLK (BTOT / SPB) // 2048 fused blocks
#define SSTR 576          // LDS floats per sample: 24 rows x 24 cols, dense

// ---- kernel 1: build V (Vr/Vi, row-major i*16+k) and W2 -------------------
__global__ __launch_bounds__(64) void prep_kernel(
    const float* __restrict__ qparams, const float* __restrict__ cls_w,
    float* __restrict__ prep)   // [0:256)=Vr, [256:512)=Vi, [512:576)=W2
{
    const int t = threadIdx.x;
    {   // W2[j][i] = sum_w cls_w[j][w] * sign_w(i)
        int j = t >> 4, i = t & 15;
        float acc = 0.f;
        #pragma unroll
        for (int w = 0; w < 4; ++w)
            acc += cls_w[j * 4 + w] * ((i & (8 >> w)) ? -1.f : 1.f);
        prep[512 + j * 16 + i] = acc;
    }
    if (t < 16) {
        // simulate variational layers on basis state e_t -> column t of U
        float pr[16], pi[16];
        #pragma unroll
        for (int i = 0; i < 16; ++i) { pr[i] = (i == t) ? 1.f : 0.f; pi[i] = 0.f; }
        #pragma unroll
        for (int layer = 0; layer < 3; ++layer) {
            #pragma unroll
            for (int w = 0; w < 4; ++w) {
                const float* qp = qparams + (layer * 4 + w) * 3;
                float phi = qp[0], th = qp[1], om = qp[2];
                float c, s, ca, sa, cd, sd;
                __sincosf(0.5f * th, &s, &c);
                __sincosf(0.5f * (phi + om), &sa, &ca);
                __sincosf(0.5f * (phi - om), &sd, &cd);
                float u00r =  c * ca, u00i = -c * sa;
                float u01r = -s * cd, u01i = -s * sd;
                float u10r =  s * cd, u10i = -s * sd;
                float u11r =  c * ca, u11i =  c * sa;
                const int m = 8 >> w;   // wire 0 = MSB
                #pragma unroll
                for (int idx = 0; idx < 16; ++idx) {
                    if (idx & m) continue;
                    const int i1 = idx | m;
                    float ar = pr[idx], ai = pi[idx], br = pr[i1], bi = pi[i1];
                    pr[idx] = u00r*ar - u00i*ai + u01r*br - u01i*bi;
                    pi[idx] = u00r*ai + u00i*ar + u01r*bi + u01i*br;
                    pr[i1]  = u10r*ar - u10i*ai + u11r*br - u11i*bi;
                    pi[i1]  = u10r*ai + u10i*ar + u11r*bi + u11i*br;
                }
            }
            #pragma unroll
            for (int w = 0; w < 3; ++w) {  // CNOT ladder (register renames)
                const int mc = 8 >> w, mt = 8 >> (w + 1);
                #pragma unroll
                for (int idx = 0; idx < 16; ++idx) {
                    if ((idx & mc) && !(idx & mt)) {
                        const int i1 = idx | mt;
                        float tr = pr[idx], ti = pi[idx];
                        pr[idx] = pr[i1]; pi[idx] = pi[i1];
                        pr[i1] = tr;      pi[i1] = ti;
                    }
                }
            }
        }
        // fold (-i)^popcount(column t)
        const int p = __popc(t) & 3;
        #pragma unroll
        for (int i = 0; i < 16; ++i) {
            float re = pr[i], im = pi[i], vr, vi;
            if (p == 0)      { vr = re;  vi = im;  }
            else if (p == 1) { vr = im;  vi = -re; }
            else if (p == 2) { vr = -re; vi = -im; }
            else             { vr = -im; vi = re;  }
            prep[i * 16 + t]       = vr;
            prep[256 + i * 16 + t] = vi;
        }
    }
}

// ---- kernel 2: DMA-stage->pool->encode->circuit->classify + BN partials ---
__global__ __launch_bounds__(256) void fused_kernel(
    const float* __restrict__ x,
    const float* __restrict__ enc_w, const float* __restrict__ enc_b,
    const float* __restrict__ prep, const float* __restrict__ cls_b,
    float* __restrict__ preBN, float* __restrict__ partials)
{
    __shared__ float sx[SPB * SSTR];     // 36864 B: 24x24 region, dense
    __shared__ float sVr[16 * 17];       // stride 17: 17k mod 32 injective
    __shared__ float sVi[16 * 17];
    __shared__ float sW2[4 * 17];
    __shared__ float red[4][8];

    const int tid = threadIdx.x;
    const int s0  = blockIdx.x * SPB;
    const float4* xb = (const float4*)x;

    // ---- stage 24x24 region of 16 samples via async global->LDS DMA ------
    // 144 f4/sample, 2304 f4/block = 9 exact rounds of 256. LDS dest is
    // dense gid*16 = wave-uniform base + lane*16 (DMA rule).
    {
        const int waveBase = tid & ~63;            // wave-uniform
        #pragma unroll
        for (int it = 0; it < 9; ++it) {
            const int gid  = it * 256 + tid;
            const int c    = gid / 144;            // sample within block
            const int o    = gid - c * 144;        // f4 within 24x24 region
            const int row  = o / 6;
            const int col4 = o - row * 6;
            const float4* gsrc = xb + (size_t)(s0 + c) * 196 + row * 7 + col4;
            float* lbase = &sx[(it * 256 + waveBase) * 4];
            __builtin_amdgcn_global_load_lds(
                (const __attribute__((address_space(1))) void*)gsrc,
                (__attribute__((address_space(3))) void*)lbase,
                16, 0, 0);
        }
    }

    // ---- copy prep constants into banked LDS (overlaps DMA) --------------
    #pragma unroll
    for (int g0 = 0; g0 < 576; g0 += 256) {
        int g = g0 + tid;
        if (g < 576) {
            float v = prep[g];
            int row = (g >> 4) & 15, col = g & 15;
            if (g < 256)      sVr[row * 17 + col] = v;
            else if (g < 512) sVi[row * 17 + col] = v;
            else              sW2[(g - 512) / 16 * 17 + col] = v;
        }
    }
    __syncthreads();   // drains vmcnt (DMA) + lgkmcnt

    // ---- pool: thread (s, cell); row order rotated by s mod 6 ------------
    const int s = tid >> 4, cell = tid & 15;
    const int cr = cell >> 2, cc = cell & 3;
    int srot = s;                                   // srot = s mod 6
    srot -= (srot >= 12) ? 12 : ((srot >= 6) ? 6 : 0);
    const float* sb = &sx[s * SSTR + cr * 6 * 24 + cc * 6];
    float sum = 0.f;
    #pragma unroll
    for (int rr = 0; rr < 6; ++rr) {
        int r = rr + srot; r -= (r >= 6) ? 6 : 0;   // (rr + s) mod 6, correct
        const float2* rp = (const float2*)(sb + r * 24);
        float2 a = rp[0], b = rp[1], c2 = rp[2];
        sum += (a.x + a.y) + (b.x + b.y) + (c2.x + c2.y);
    }
    const float pv = sum * (1.f / 36.f);

    // ---- encode: z_j = sum_cells enc_w[j][cell]*pv, 16-lane xor-reduce ---
    float z[4];
    #pragma unroll
    for (int j = 0; j < 4; ++j) z[j] = enc_w[j * 16 + cell] * pv;
    #pragma unroll
    for (int m = 1; m <= 8; m <<= 1) {
        #pragma unroll
        for (int j = 0; j < 4; ++j) z[j] += __shfl_xor(z[j], m, 64);
    }
    #pragma unroll
    for (int j = 0; j < 4; ++j) z[j] += enc_b[j];

    // ---- product state r_k ------------------------------------------------
    float cz[4], sz[4];
    #pragma unroll
    for (int j = 0; j < 4; ++j) __sincosf(0.5f * z[j], &sz[j], &cz[j]);
    float a01[4] = {cz[0]*cz[1], cz[0]*sz[1], sz[0]*cz[1], sz[0]*sz[1]};
    float a23[4] = {cz[2]*cz[3], cz[2]*sz[3], sz[2]*cz[3], sz[2]*sz[3]};
    float rv[16];
    #pragma unroll
    for (int k = 0; k < 16; ++k) rv[k] = a01[k >> 2] * a23[k & 3];

    // ---- matvec row i = cell; prob; partial classifier --------------------
    float ar = 0.f, ai = 0.f;
    #pragma unroll
    for (int k = 0; k < 16; ++k) {
        ar += sVr[cell * 17 + k] * rv[k];
        ai += sVi[cell * 17 + k] * rv[k];
    }
    const float prob = ar * ar + ai * ai;
    float out[4];
    #pragma unroll
    for (int j = 0; j < 4; ++j) out[j] = sW2[j * 17 + cell] * prob;
    #pragma unroll
    for (int m = 1; m <= 8; m <<= 1) {
        #pragma unroll
        for (int j = 0; j < 4; ++j) out[j] += __shfl_xor(out[j], m, 64);
    }
    #pragma unroll
    for (int j = 0; j < 4; ++j) out[j] += cls_b[j];

    if (cell == 0)
        ((float4*)preBN)[s0 + s] = make_float4(out[0], out[1], out[2], out[3]);

    // ---- BN partials: one contribution per sample (cell==0 lanes) ---------
    const float w = (cell == 0) ? 1.f : 0.f;
    float v8[8] = {out[0]*w, out[1]*w, out[2]*w, out[3]*w,
                   out[0]*out[0]*w, out[1]*out[1]*w, out[2]*out[2]*w, out[3]*out[3]*w};
    #pragma unroll
    for (int m = 0; m < 8; ++m) {
        v8[m] += __shfl_down(v8[m], 32, 64);
        v8[m] += __shfl_down(v8[m], 16, 64);
    }
    const int wave = tid >> 6, lane = tid & 63;
    if (lane == 0) {
        #pragma unroll
        for (int m = 0; m < 8; ++m) red[wave][m] = v8[m];
    }
    __syncthreads();
    // plain coalesced store to a private slot — no atomics
    if (tid < 8)
        partials[blockIdx.x * 8 + tid] =
            red[0][tid] + red[1][tid] + red[2][tid] + red[3][tid];
}

// ---- kernel 3: reduce partials (redundantly per block) + batch-norm -------
__global__ __launch_bounds__(256) void bn_kernel(
    const float* __restrict__ partials,
    const float* __restrict__ gamma, const float* __restrict__ beta,
    float* __restrict__ out)
{
    const int tid = threadIdx.x;
    float acc[8] = {0, 0, 0, 0, 0, 0, 0, 0};
    const float4* p4 = (const float4*)partials;
    #pragma unroll
    for (int it = 0; it < NBLK / 256; ++it) {
        int b = it * 256 + tid;
        float4 a = p4[b * 2], c = p4[b * 2 + 1];
        acc[0] += a.x; acc[1] += a.y; acc[2] += a.z; acc[3] += a.w;
        acc[4] += c.x; acc[5] += c.y; acc[6] += c.z; acc[7] += c.w;
    }
    #pragma unroll
    for (int off = 32; off >= 1; off >>= 1) {
        #pragma unroll
        for (int m = 0; m < 8; ++m) acc[m] += __shfl_xor(acc[m], off, 64);
    }
    __shared__ float red[4][8];
    const int wave = tid >> 6, lane = tid & 63;
    if (lane == 0) {
        #pragma unroll
        for (int m = 0; m < 8; ++m) red[wave][m] = acc[m];
    }
    __syncthreads();
    float sums[8];
    #pragma unroll
    for (int m = 0; m < 8; ++m)
        sums[m] = red[0][m] + red[1][m] + red[2][m] + red[3][m];

    const int s = blockIdx.x * 256 + tid;
    const float invB = 1.f / (float)BTOT;
    float4 v = ((const float4*)out)[s];
    float o[4] = {v.x, v.y, v.z, v.w};
    #pragma unroll
    for (int j = 0; j < 4; ++j) {
        float mu   = sums[j] * invB;
        float var  = sums[4 + j] * invB - mu * mu;
        float rstd = rsqrtf(var + 1e-5f);
        o[j] = (o[j] - mu) * rstd * gamma[j] + beta[j];
    }
    ((float4*)out)[s] = make_float4(o[0], o[1], o[2], o[3]);
}

extern "C" void kernel_launch(void* const* d_in, const int* in_sizes, int n_in,
                              void* d_out, int out_size, void* d_ws, size_t ws_size,
                              hipStream_t stream)
{
    const float* x        = (const float*)d_in[0];
    const float* enc_w    = (const float*)d_in[1];
    const float* enc_b    = (const float*)d_in[2];
    const float* qparams  = (const float*)d_in[3];
    const float* cls_w    = (const float*)d_in[4];
    const float* cls_b    = (const float*)d_in[5];
    const float* bn_gamma = (const float*)d_in[6];
    const float* bn_beta  = (const float*)d_in[7];

    float* prep     = (float*)d_ws;      // 576 floats (V, W2)
    float* partials = prep + 576;        // 2048 * 8 floats (written, no init)
    float* outp     = (float*)d_out;     // pre-BN scratch == final out

    prep_kernel<<<1, 64, 0, stream>>>(qparams, cls_w, prep);
    fused_kernel<<<NBLK, 256, 0, stream>>>(x, enc_w, enc_b, prep, cls_b,
                                           outp, partials);
    bn_kernel<<<128, 256, 0, stream>>>(partials, bn_gamma, bn_beta, outp);
}